// Round 6
// baseline (195.327 us; speedup 1.0000x reference)
//
#include <hip/hip_runtime.h>

// CascadeHierarchicalEmbedding, R6: occupancy-first persistent per-wave pipeline.
// - emb2 (2.5 MB, L2-resident): per-lane direct loads in compute layout (no LDS).
// - emb0/emb1: 4 KB/wave each, single-buffered, filled via global_load_lds with
//   XOR-swizzled global source (linear LDS dest).
// - W1 fragments in LDS (16 KB per block, shared by 8 waves) -> VGPR ~100.
// - 8 waves/block, 80 KB LDS -> 2 blocks/CU = 16 waves/CU resident.
// - Pinned VMEM issue order per iter: C(emb2,4) | A(gathers t+nw,8) | B(ids,9)
//   | compute | D(stores,4). Top-of-loop s_waitcnt vmcnt(13) == B+D -> A done.

#define WPB 8       // waves per block (512 threads)
#define NBLK 512    // grid: 512 blocks x 8 waves = 4096 waves = exactly resident

typedef float f32x4 __attribute__((ext_vector_type(4)));
typedef short v8s __attribute__((ext_vector_type(8)));
typedef __attribute__((address_space(3))) uint32_t lds_u32_t;
typedef __attribute__((address_space(1))) const uint32_t glb_u32_t;

static __device__ __forceinline__ unsigned short bf16_rne(float f) {
  union { float f; unsigned int u; } a; a.f = f;
  return (unsigned short)((a.u + 0x7FFFu + ((a.u >> 16) & 1u)) >> 16);
}

// Pack W1 (f32 [128][32]) into bf16 A-fragments (W1^T). gate0: frags 0..7,
// gate1: frags 8..15. fragid = gate*8 + kt*2 + nt; elem (lane,j):
// k = kt*32 + (lane>>4)*8 + j, o = nt*16 + (lane&15) -> w1[k][o].
__global__ __launch_bounds__(256) void prep_frags(
    const float* __restrict__ g0w1, const float* __restrict__ g1w1,
    unsigned short* __restrict__ wsf) {
  int t = blockIdx.x * 256 + threadIdx.x;
  if (t >= 1024) return;
  int lane = t & 63, fragid = t >> 6;
  int gate = fragid >> 3, kt = (fragid >> 1) & 3, nt = fragid & 1;
  const float* __restrict__ w1 = gate ? g1w1 : g0w1;
#pragma unroll
  for (int j = 0; j < 8; ++j) {
    int k = kt * 32 + ((lane >> 4) << 3) + j;
    int o = nt * 16 + (lane & 15);
    wsf[fragid * 512 + lane * 8 + j] = bf16_rne(w1[k * 32 + o]);
  }
}

// One gate level: z = W1^T x (bf16-hi), W frags read from LDS; relu+layer2
// per lane, 2-shuffle reduce, sigmoid, blend cur in place. b1 in acc init.
static __device__ __forceinline__ void gate_apply(
    const float (&fine)[16], float (&cur)[16], const uint4* wfl, int lane,
    f32x4 b1a, f32x4 b1b, f32x4 w2a, f32x4 w2b, float b2s) {
  v8s xf0, xf1, xc0, xc1;
#pragma unroll
  for (int e = 0; e < 8; ++e) {
    xf0[e] = (short)bf16_rne(fine[e]);
    xf1[e] = (short)bf16_rne(fine[8 + e]);
    xc0[e] = (short)bf16_rne(cur[e]);
    xc1[e] = (short)bf16_rne(cur[8 + e]);
  }
  uint4 w0 = wfl[0 * 64 + lane], w1 = wfl[1 * 64 + lane];
  uint4 w2v = wfl[2 * 64 + lane], w3 = wfl[3 * 64 + lane];
  uint4 w4 = wfl[4 * 64 + lane], w5 = wfl[5 * 64 + lane];
  uint4 w6 = wfl[6 * 64 + lane], w7 = wfl[7 * 64 + lane];
  f32x4 acc0 = b1a, acc1 = b1b;
  acc0 = __builtin_amdgcn_mfma_f32_16x16x32_bf16(*(const v8s*)&w0, xf0, acc0, 0, 0, 0);
  acc1 = __builtin_amdgcn_mfma_f32_16x16x32_bf16(*(const v8s*)&w1, xf0, acc1, 0, 0, 0);
  acc0 = __builtin_amdgcn_mfma_f32_16x16x32_bf16(*(const v8s*)&w2v, xf1, acc0, 0, 0, 0);
  acc1 = __builtin_amdgcn_mfma_f32_16x16x32_bf16(*(const v8s*)&w3, xf1, acc1, 0, 0, 0);
  acc0 = __builtin_amdgcn_mfma_f32_16x16x32_bf16(*(const v8s*)&w4, xc0, acc0, 0, 0, 0);
  acc1 = __builtin_amdgcn_mfma_f32_16x16x32_bf16(*(const v8s*)&w5, xc0, acc1, 0, 0, 0);
  acc0 = __builtin_amdgcn_mfma_f32_16x16x32_bf16(*(const v8s*)&w6, xc1, acc0, 0, 0, 0);
  acc1 = __builtin_amdgcn_mfma_f32_16x16x32_bf16(*(const v8s*)&w7, xc1, acc1, 0, 0, 0);
  float zp = 0.f;
#pragma unroll
  for (int j = 0; j < 4; ++j)
    zp += fmaxf(acc0[j], 0.f) * w2a[j] + fmaxf(acc1[j], 0.f) * w2b[j];
  zp += __shfl_xor(zp, 16);
  zp += __shfl_xor(zp, 32);
  float g = 1.f / (1.f + __expf(-(zp + b2s)));
#pragma unroll
  for (int e = 0; e < 16; ++e) cur[e] = fmaf(g, fine[e] - cur[e], cur[e]);
}

__global__ __launch_bounds__(512, 4) void cascade_pipe(
    const int* __restrict__ ids0, const int* __restrict__ ids1,
    const int* __restrict__ ids2,
    const float* __restrict__ emb0, const float* __restrict__ emb1,
    const float* __restrict__ emb2,
    const uint4* __restrict__ wfrag,
    const float* __restrict__ b1_0, const float* __restrict__ w2_0,
    const float* __restrict__ b2_0,
    const float* __restrict__ b1_1, const float* __restrict__ w2_1,
    const float* __restrict__ b2_1,
    float* __restrict__ out, int n) {
  __shared__ uint4 WF[1024];            // 16 KB: frag f at WF[f*64 + lane]
  __shared__ float4 EB[WPB][2][256];    // per wave: [0]=emb1, [1]=emb0, 4 KB ea
  const int tid = threadIdx.x, lane = tid & 63, wave = tid >> 6;
  const int q = lane >> 4, t16 = lane & 15;
  const int ntiles = n >> 4;            // n divisible by 16
  const int nw = NBLK * WPB;
  int tile = blockIdx.x * WPB + wave;

  // stage W fragments into LDS (512 thr x 2 x 16 B = 16 KB, linear)
  __builtin_amdgcn_global_load_lds(
      (glb_u32_t*)((const char*)wfrag + tid * 16),
      (lds_u32_t*)(uint32_t*)&WF[tid], 16, 0, 0);
  __builtin_amdgcn_global_load_lds(
      (glb_u32_t*)((const char*)wfrag + 8192 + tid * 16),
      (lds_u32_t*)(uint32_t*)&WF[512 + tid], 16, 0, 0);

  // layer-2 params (per-lane, q-dependent)
  const f32x4 b1a0 = *(const f32x4*)&b1_0[q * 4], b1b0 = *(const f32x4*)&b1_0[16 + q * 4];
  const f32x4 w2a0 = *(const f32x4*)&w2_0[q * 4], w2b0 = *(const f32x4*)&w2_0[16 + q * 4];
  const f32x4 b1a1 = *(const f32x4*)&b1_1[q * 4], b1b1 = *(const f32x4*)&b1_1[16 + q * 4];
  const f32x4 w2a1 = *(const f32x4*)&w2_1[q * 4], w2b1 = *(const f32x4*)&w2_1[16 + q * 4];
  const float b2s0 = b2_0[0], b2s1 = b2_1[0];

  // 8 gathers for emb1+emb0 of a tile, XOR-swizzled via global source,
  // linear LDS dest. Row covered by instr s = s*4+q, chunk = t16.
  auto issueA = [&](const int (&i1)[4], const int (&i0)[4]) {
#pragma unroll
    for (int s = 0; s < 4; ++s) {
      int swb = ((t16 ^ (s * 4 + q)) << 4);
      __builtin_amdgcn_global_load_lds(
          (glb_u32_t*)((const char*)emb1 + (((long)i1[s]) << 8) + swb),
          (lds_u32_t*)(uint32_t*)&EB[wave][0][s * 64], 16, 0, 0);
      __builtin_amdgcn_global_load_lds(
          (glb_u32_t*)((const char*)emb0 + (((long)i0[s]) << 8) + swb),
          (lds_u32_t*)(uint32_t*)&EB[wave][1][s * 64], 16, 0, 0);
    }
  };

  // prologue: ids for tile0's gathers + loop-carried prefetch ids
  int jA1[4], jA0[4];  // ids for A-issue (tile+nw at loop time)
  int jC2;             // id for C (this tile's emb2 row, per-lane token t16)
  {
    int a1[4], a0[4];
    int tb = (tile << 4);
#pragma unroll
    for (int s = 0; s < 4; ++s) {
      a1[s] = ids1[tb + s * 4 + q];
      a0[s] = ids0[tb + s * 4 + q];
    }
    jC2 = ids2[tb + t16];
    int tn = tile + nw; if (tn >= ntiles) tn = 0;
    int tb2 = (tn << 4);
#pragma unroll
    for (int s = 0; s < 4; ++s) {
      jA1[s] = ids1[tb2 + s * 4 + q];
      jA0[s] = ids0[tb2 + s * 4 + q];
    }
    __syncthreads();          // WF staged (barrier drains vmcnt), ids in regs
    issueA(a1, a0);           // gathers for tile0
    asm volatile("s_waitcnt vmcnt(0)" ::: "memory");  // one-time drain
    __builtin_amdgcn_sched_barrier(0);
  }

  for (; tile < ntiles; tile += nw) {
    // A(t) retired iff outstanding <= B(9)+D(4) = 13
    asm volatile("s_waitcnt vmcnt(13)" ::: "memory");
    __builtin_amdgcn_sched_barrier(0);

    // fine frags from LDS (swizzled chunks of row t16)
    float f1v[16], f0v[16];
#pragma unroll
    for (int e = 0; e < 4; ++e) {
      int ci = (2 * q + (e & 1) + 8 * (e >> 1)) ^ t16;
      *(float4*)&f1v[e * 4] = EB[wave][0][t16 * 16 + ci];
      *(float4*)&f0v[e * 4] = EB[wave][1][t16 * 16 + ci];
    }
    asm volatile("s_waitcnt lgkmcnt(0)" ::: "memory");  // reads done -> LDS free
    __builtin_amdgcn_sched_barrier(0);

    // C: emb2 row (this tile, compute layout, L2-resident) -> registers
    float curv[16];
    {
      const char* rb = (const char*)emb2 + (((long)jC2) << 8) + q * 32;
      *(float4*)&curv[0]  = *(const float4*)(rb);
      *(float4*)&curv[4]  = *(const float4*)(rb + 16);
      *(float4*)&curv[8]  = *(const float4*)(rb + 128);
      *(float4*)&curv[12] = *(const float4*)(rb + 144);
    }
    __builtin_amdgcn_sched_barrier(0);

    // A: gathers for tile+nw (prefetch; latency hidden across iterations)
    issueA(jA1, jA0);
    __builtin_amdgcn_sched_barrier(0);

    // B: prefetch ids (9 loads): emb2 id for tile+nw, emb0/1 ids for tile+2nw
    {
      int tn = tile + nw; if (tn >= ntiles) tn = 0;
      int tn2 = tile + 2 * nw; if (tn2 >= ntiles) tn2 = 0;
      jC2 = ids2[(tn << 4) + t16];
      int tb2 = (tn2 << 4);
#pragma unroll
      for (int s = 0; s < 4; ++s) {
        jA1[s] = ids1[tb2 + s * 4 + q];
        jA0[s] = ids0[tb2 + s * 4 + q];
      }
    }
    __builtin_amdgcn_sched_barrier(0);

    // compute: gate1 (fine=emb1) then gate0 (fine=emb0); W frags from LDS
    gate_apply(f1v, curv, &WF[512], lane, b1a1, b1b1, w2a1, w2b1, b2s1);
    gate_apply(f0v, curv, &WF[0],   lane, b1a0, b1b0, w2a0, w2b0, b2s0);

    // D: store token (tile*16 + t16), 4 x 16 B
    long tok = ((long)tile << 4) + t16;
    float4* op = (float4*)out + (tok << 4);
    op[2 * q + 0]     = float4{curv[0], curv[1], curv[2], curv[3]};
    op[2 * q + 1]     = float4{curv[4], curv[5], curv[6], curv[7]};
    op[8 + 2 * q + 0] = float4{curv[8], curv[9], curv[10], curv[11]};
    op[8 + 2 * q + 1] = float4{curv[12], curv[13], curv[14], curv[15]};
  }
}

extern "C" void kernel_launch(void* const* d_in, const int* in_sizes, int n_in,
                              void* d_out, int out_size, void* d_ws,
                              size_t ws_size, hipStream_t stream) {
  const int* ids0 = (const int*)d_in[0];
  const int* ids1 = (const int*)d_in[1];
  const int* ids2 = (const int*)d_in[2];
  const float* emb0 = (const float*)d_in[3];
  const float* emb1 = (const float*)d_in[4];
  const float* emb2 = (const float*)d_in[5];
  const float* g0w1 = (const float*)d_in[6];
  const float* g0b1 = (const float*)d_in[7];
  const float* g0w2 = (const float*)d_in[8];
  const float* g0b2 = (const float*)d_in[9];
  const float* g1w1 = (const float*)d_in[10];
  const float* g1b1 = (const float*)d_in[11];
  const float* g1w2 = (const float*)d_in[12];
  const float* g1b2 = (const float*)d_in[13];
  float* out = (float*)d_out;

  int n = in_sizes[0];  // B*H tokens

  hipLaunchKernelGGL(prep_frags, dim3(4), dim3(256), 0, stream,
                     g0w1, g1w1, (unsigned short*)d_ws);

  hipLaunchKernelGGL(cascade_pipe, dim3(NBLK), dim3(512), 0, stream,
                     ids0, ids1, ids2, emb0, emb1, emb2,
                     (const uint4*)d_ws,
                     g0b1, g0w2, g0b2,
                     g1b1, g1w2, g1b2,
                     out, n);
}